// Round 1
// 428.041 us; speedup vs baseline: 1.1217x; 1.1217x over previous
//
#include <hip/hip_runtime.h>
#include <hip/hip_bf16.h>
#include <stdint.h>

#define B_ 32
#define N_ 1024
#define D_ 1024

typedef __bf16 bf16x8 __attribute__((ext_vector_type(8)));
typedef float f32x4 __attribute__((ext_vector_type(4)));

static __device__ __forceinline__ unsigned short f2bf(float f) {
    union { float f; unsigned u; } v; v.f = f;
    unsigned r = v.u + 0x7fffu + ((v.u >> 16) & 1u);   // round-to-nearest-even
    return (unsigned short)(r >> 16);
}

static __device__ __forceinline__ void gld_lds16(const void* g, void* l) {
    __builtin_amdgcn_global_load_lds(
        (const __attribute__((address_space(1))) void*)g,
        (__attribute__((address_space(3))) void*)l, 16, 0, 0);
}

// ---------------------------------------------------------------------------
// K1: wave-per-row softmax stats. 4 rows/block, no __syncthreads.
// pb = bf16(softmax(x)), xb = bf16(x), lse = max + log(sum exp(x-max)).
// ---------------------------------------------------------------------------
__global__ __launch_bounds__(256) void prep_kernel(const float* __restrict__ x,
        unsigned short* __restrict__ pb, unsigned short* __restrict__ xb,
        float* __restrict__ lse) {
    int row  = blockIdx.x * 4 + (threadIdx.x >> 6);
    int lane = threadIdx.x & 63;
    const float4* xr = (const float4*)(x + (size_t)row * D_);

    float4 v[4];
    #pragma unroll
    for (int q = 0; q < 4; q++) v[q] = xr[lane + 64 * q];

    float m = -1e30f;
    #pragma unroll
    for (int q = 0; q < 4; q++)
        m = fmaxf(m, fmaxf(fmaxf(v[q].x, v[q].y), fmaxf(v[q].z, v[q].w)));
    #pragma unroll
    for (int o = 1; o < 64; o <<= 1) m = fmaxf(m, __shfl_xor(m, o, 64));

    float4 e[4];
    float s = 0.0f;
    #pragma unroll
    for (int q = 0; q < 4; q++) {
        e[q].x = __expf(v[q].x - m); e[q].y = __expf(v[q].y - m);
        e[q].z = __expf(v[q].z - m); e[q].w = __expf(v[q].w - m);
        s += e[q].x + e[q].y + e[q].z + e[q].w;
    }
    #pragma unroll
    for (int o = 1; o < 64; o <<= 1) s += __shfl_xor(s, o, 64);
    float inv = 1.0f / s;

    ushort4* pr = (ushort4*)(pb + (size_t)row * D_);
    ushort4* xw = (ushort4*)(xb + (size_t)row * D_);
    #pragma unroll
    for (int q = 0; q < 4; q++) {
        ushort4 pu, xu;
        pu.x = f2bf(e[q].x * inv); pu.y = f2bf(e[q].y * inv);
        pu.z = f2bf(e[q].z * inv); pu.w = f2bf(e[q].w * inv);
        xu.x = f2bf(v[q].x); xu.y = f2bf(v[q].y);
        xu.z = f2bf(v[q].z); xu.w = f2bf(v[q].w);
        pr[lane + 64 * q] = pu;
        xw[lane + 64 * q] = xu;
    }
    if (lane == 0) lse[row] = m + logf(s);
}

// ---------------------------------------------------------------------------
// K2/K4: batched bf16 GEMM, C[m][n] = sum_k A[m][k]*B[n][k], fused epilogues.
// 256x256 tile, BK=32, 8 waves (2Mx4N), per-wave 128x64 via 8x4 mfma 16x16x32.
// Phase-interleaved pipeline: 2 phases/K-tile, counted vmcnt (never 0 in
// steady state), raw s_barrier (no implicit vmem drain), setprio around MFMA.
// Staging runs 3 chunk-pairs (1.5 K-tiles) ahead into 2x double-buffered LDS.
// LDS k-group XOR swizzle (g ^= (row>>1)&3) on SOURCE addr; linear DMA dest.
// MODE 0 (gemm1): e = exp(acc - lse[col]) -> bf16 store + rowsum atomics.
// MODE 1 (gemm2): out = acc / rowsum[row], fp32 store.
// ---------------------------------------------------------------------------
template<int MODE>
__global__ __launch_bounds__(512) void gemm_bt(const unsigned short* __restrict__ Ag,
        const unsigned short* __restrict__ Bg, void* __restrict__ Cg,
        const float* __restrict__ lse, float* __restrict__ rowsum) {
    const int K = 1024;
    int b = blockIdx.z;
    const unsigned short* A  = Ag + (size_t)b * N_ * K;
    const unsigned short* Bm = Bg + (size_t)b * N_ * K;
    int m0 = blockIdx.y * 256, n0 = blockIdx.x * 256;

    // [A buf0 | A buf1 | B buf0 | B buf1], 16 KB each = 64 KB total
    __shared__ unsigned short lds[32768];

    int t = threadIdx.x;
    int wave = t >> 6, lane = t & 63;
    int wr = wave >> 2, wc = wave & 3;        // 2 x 4 wave grid
    int fm = lane & 15, gf = lane >> 4;
    int rsw = (fm >> 1) & 3;                  // read-side swizzle term

    f32x4 acc[8][4];
    #pragma unroll
    for (int i = 0; i < 8; i++)
        #pragma unroll
        for (int j = 0; j < 4; j++)
            #pragma unroll
            for (int r = 0; r < 4; r++) acc[i][j][r] = 0.0f;

    // staging slice (per thread, constant across pairs):
    // chunk = 8 KB = 128 rows x 64 B; thread handles (row, k-slot s) 16 B.
    int rr = t >> 2, s = t & 3;
    int sg = s ^ ((rr >> 1) & 3);             // inverse-swizzled source k-group
    int rbase = rr + (rr & 64);               // rr<64 -> rr ; rr>=64 -> rr+64 (second half)

    // pair g: K-tile tg=g>>1, chunk qg=g&1 (rows qg*64.. in both 128-halves),
    // buffer bg=tg&1. Issued at phase p = g-3 -> 3 pairs (6 glds) in flight.
    auto stage = [&](int g) {
        int tg = g >> 1, qg = g & 1, bg = tg & 1;
        int row = qg * 64 + rbase;
        const unsigned short* sa = A  + (size_t)(m0 + row) * K + tg * 32 + sg * 8;
        const unsigned short* sb = Bm + (size_t)(n0 + row) * K + tg * 32 + sg * 8;
        gld_lds16(sa, &lds[bg * 8192 + row * 32 + s * 8]);
        gld_lds16(sb, &lds[16384 + bg * 8192 + row * 32 + s * 8]);
    };

    // prologue: tiles 0,1(chunk0) in flight; wait pairs 0,1 (tile 0) landed.
    stage(0); stage(1); stage(2);
    asm volatile("s_waitcnt vmcnt(2)" ::: "memory");
    __builtin_amdgcn_s_barrier();

    for (int tt = 0; tt < 32; ++tt) {
        int bb = tt & 1;
        const unsigned short* LA = &lds[bb * 8192];
        const unsigned short* LB = &lds[16384 + bb * 8192];
        bf16x8 bv[4];
        #pragma unroll
        for (int q = 0; q < 2; ++q) {
            if (q == 0) {                     // B frags: read once per K-tile
                #pragma unroll
                for (int j = 0; j < 4; ++j) {
                    int row = wc * 64 + j * 16 + fm;
                    bv[j] = *(const bf16x8*)&LB[row * 32 + (gf ^ rsw) * 8];
                }
            }
            bf16x8 av[4];
            #pragma unroll
            for (int i2 = 0; i2 < 4; ++i2) {  // A quadrant q (rows 64q..64q+63 of wave half)
                int row = wr * 128 + (q * 4 + i2) * 16 + fm;
                av[i2] = *(const bf16x8*)&LA[row * 32 + (gf ^ rsw) * 8];
            }
            int g = 2 * tt + q + 3;
            if (g < 64) stage(g);             // prefetch, 1.5 tiles ahead

            __builtin_amdgcn_s_barrier();
            asm volatile("s_waitcnt lgkmcnt(0)" ::: "memory");
            __builtin_amdgcn_sched_barrier(0);
            __builtin_amdgcn_s_setprio(1);
            #pragma unroll
            for (int i2 = 0; i2 < 4; ++i2)
                #pragma unroll
                for (int j = 0; j < 4; ++j)
                    acc[q * 4 + i2][j] = __builtin_amdgcn_mfma_f32_16x16x32_bf16(
                        av[i2], bv[j], acc[q * 4 + i2][j], 0, 0, 0);
            __builtin_amdgcn_s_setprio(0);
            if (q == 1) {                     // K-tile boundary: counted wait
                if (tt < 30)       asm volatile("s_waitcnt vmcnt(2)" ::: "memory");
                else if (tt == 30) asm volatile("s_waitcnt vmcnt(0)" ::: "memory");
            }
            __builtin_amdgcn_s_barrier();
        }
    }

    // epilogue: C/D layout col=lane&15, row=(lane>>4)*4+reg
    int cr = (lane >> 4) * 4;
    int cc = lane & 15;

    if (MODE == 0) {
        unsigned short* Co = (unsigned short*)Cg + (size_t)b * (size_t)N_ * N_;
        float lsev[4];
        #pragma unroll
        for (int j = 0; j < 4; j++) lsev[j] = lse[b * N_ + n0 + wc * 64 + j * 16 + cc];
        float rsum[32];
        #pragma unroll
        for (int q = 0; q < 32; q++) rsum[q] = 0.0f;
        #pragma unroll
        for (int i = 0; i < 8; i++) {
            #pragma unroll
            for (int r = 0; r < 4; r++) {
                int row = m0 + wr * 128 + i * 16 + cr + r;
                size_t ro = (size_t)row * N_;
                #pragma unroll
                for (int j = 0; j < 4; j++) {
                    int col = n0 + wc * 64 + j * 16 + cc;
                    float ev = __expf(acc[i][j][r] - lsev[j]);   // always in [e^-14, e^-1]
                    unsigned short eb = f2bf(ev);
                    union { unsigned u; float f; } bk; bk.u = ((unsigned)eb) << 16;
                    Co[ro + col] = eb;
                    rsum[i * 4 + r] += bk.f;                     // sum the ROUNDED value
                }
            }
        }
        #pragma unroll
        for (int q = 0; q < 32; q++) {
            float sv = rsum[q];
            sv += __shfl_xor(sv, 1, 64);
            sv += __shfl_xor(sv, 2, 64);
            sv += __shfl_xor(sv, 4, 64);
            sv += __shfl_xor(sv, 8, 64);
            rsum[q] = sv;
        }
        if (cc == 0) {
            #pragma unroll
            for (int q = 0; q < 32; q++) {
                int row = m0 + wr * 128 + (q >> 2) * 16 + cr + (q & 3);
                atomicAdd(&rowsum[b * N_ + row], rsum[q]);
            }
        }
    } else {
        float* Co = (float*)Cg + (size_t)b * (size_t)N_ * N_;
        #pragma unroll
        for (int i = 0; i < 8; i++) {
            #pragma unroll
            for (int r = 0; r < 4; r++) {
                int row = m0 + wr * 128 + i * 16 + cr + r;
                float inv = 1.0f / rowsum[b * N_ + row];
                size_t ro = (size_t)row * N_;
                #pragma unroll
                for (int j = 0; j < 4; j++) {
                    int col = n0 + wc * 64 + j * 16 + cc;
                    Co[ro + col] = acc[i][j][r] * inv;
                }
            }
        }
    }
}

// ---------------------------------------------------------------------------
// K3: bf16 transpose per batch: xb[b][j][d] -> xbT[b][d][j], 64x64 tiles.
// ---------------------------------------------------------------------------
__global__ __launch_bounds__(256) void transpose_kernel(const unsigned short* __restrict__ in,
        unsigned short* __restrict__ out) {
    int b  = blockIdx.z;
    int j0 = blockIdx.y * 64;
    int d0 = blockIdx.x * 64;
    __shared__ unsigned short tile[64][66];
    const unsigned short* ip = in + ((size_t)b * N_ + j0) * D_ + d0;
    int t = threadIdx.x;
    #pragma unroll
    for (int c = t; c < 512; c += 256) {
        int r = c >> 3, col = (c & 7) * 8;
        uint4 val = *(const uint4*)(ip + (size_t)r * D_ + col);
        unsigned int* dst = (unsigned int*)&tile[r][col];
        dst[0] = val.x; dst[1] = val.y; dst[2] = val.z; dst[3] = val.w;
    }
    __syncthreads();
    unsigned short* op = out + ((size_t)b * D_ + d0) * N_ + j0;
    #pragma unroll
    for (int c = t; c < 512; c += 256) {
        int r = c >> 3, col = (c & 7) * 8;
        unsigned short vals[8];
        #pragma unroll
        for (int k = 0; k < 8; k++) vals[k] = tile[col + k][r];
        uint4 o;
        o.x = (unsigned)vals[0] | ((unsigned)vals[1] << 16);
        o.y = (unsigned)vals[2] | ((unsigned)vals[3] << 16);
        o.z = (unsigned)vals[4] | ((unsigned)vals[5] << 16);
        o.w = (unsigned)vals[6] | ((unsigned)vals[7] << 16);
        *(uint4*)(op + (size_t)r * N_ + col) = o;
    }
}

extern "C" void kernel_launch(void* const* d_in, const int* in_sizes, int n_in,
                              void* d_out, int out_size, void* d_ws, size_t ws_size,
                              hipStream_t stream) {
    const float* x = (const float*)d_in[0];
    float* out = (float*)d_out;
    char* ws = (char*)d_ws;

    // layout: [pb 64M][xb 64M][xbT 64M][attnE 64M][lse 128K][rowsum 128K]
    unsigned short* pb    = (unsigned short*)(ws);
    unsigned short* xb    = (unsigned short*)(ws + 67108864ULL);
    unsigned short* xbT   = (unsigned short*)(ws + 134217728ULL);
    unsigned short* attnE = (unsigned short*)(ws + 201326592ULL);
    float*          lse   = (float*)(ws + 268435456ULL);
    float*          rowsum= (float*)(ws + 268566528ULL);

    hipMemsetAsync(rowsum, 0, B_ * N_ * sizeof(float), stream);
    prep_kernel<<<dim3(B_ * N_ / 4), 256, 0, stream>>>(x, pb, xb, lse);
    transpose_kernel<<<dim3(16, 16, B_), 256, 0, stream>>>(xb, xbT);
    gemm_bt<0><<<dim3(4, 4, B_), 512, 0, stream>>>(pb, xb, attnE, lse, rowsum);
    gemm_bt<1><<<dim3(4, 4, B_), 512, 0, stream>>>(attnE, xbT, out, nullptr, rowsum);
}

// Round 2
// 420.337 us; speedup vs baseline: 1.1423x; 1.0183x over previous
//
#include <hip/hip_runtime.h>
#include <hip/hip_bf16.h>
#include <stdint.h>

#define B_ 32
#define N_ 1024
#define D_ 1024

typedef __bf16 bf16x8 __attribute__((ext_vector_type(8)));
typedef float f32x4 __attribute__((ext_vector_type(4)));

static __device__ __forceinline__ unsigned short f2bf(float f) {
    union { float f; unsigned u; } v; v.f = f;
    unsigned r = v.u + 0x7fffu + ((v.u >> 16) & 1u);   // round-to-nearest-even
    return (unsigned short)(r >> 16);
}

static __device__ __forceinline__ void gld_lds16(const void* g, void* l) {
    __builtin_amdgcn_global_load_lds(
        (const __attribute__((address_space(1))) void*)g,
        (__attribute__((address_space(3))) void*)l, 16, 0, 0);
}

// ---------------------------------------------------------------------------
// K1: wave-per-row softmax stats. 4 rows/block, no __syncthreads.
// ---------------------------------------------------------------------------
__global__ __launch_bounds__(256) void prep_kernel(const float* __restrict__ x,
        unsigned short* __restrict__ pb, unsigned short* __restrict__ xb,
        float* __restrict__ lse) {
    int row  = blockIdx.x * 4 + (threadIdx.x >> 6);
    int lane = threadIdx.x & 63;
    const float4* xr = (const float4*)(x + (size_t)row * D_);

    float4 v[4];
    #pragma unroll
    for (int q = 0; q < 4; q++) v[q] = xr[lane + 64 * q];

    float m = -1e30f;
    #pragma unroll
    for (int q = 0; q < 4; q++)
        m = fmaxf(m, fmaxf(fmaxf(v[q].x, v[q].y), fmaxf(v[q].z, v[q].w)));
    #pragma unroll
    for (int o = 1; o < 64; o <<= 1) m = fmaxf(m, __shfl_xor(m, o, 64));

    float4 e[4];
    float s = 0.0f;
    #pragma unroll
    for (int q = 0; q < 4; q++) {
        e[q].x = __expf(v[q].x - m); e[q].y = __expf(v[q].y - m);
        e[q].z = __expf(v[q].z - m); e[q].w = __expf(v[q].w - m);
        s += e[q].x + e[q].y + e[q].z + e[q].w;
    }
    #pragma unroll
    for (int o = 1; o < 64; o <<= 1) s += __shfl_xor(s, o, 64);
    float inv = 1.0f / s;

    ushort4* pr = (ushort4*)(pb + (size_t)row * D_);
    ushort4* xw = (ushort4*)(xb + (size_t)row * D_);
    #pragma unroll
    for (int q = 0; q < 4; q++) {
        ushort4 pu, xu;
        pu.x = f2bf(e[q].x * inv); pu.y = f2bf(e[q].y * inv);
        pu.z = f2bf(e[q].z * inv); pu.w = f2bf(e[q].w * inv);
        xu.x = f2bf(v[q].x); xu.y = f2bf(v[q].y);
        xu.z = f2bf(v[q].z); xu.w = f2bf(v[q].w);
        pr[lane + 64 * q] = pu;
        xw[lane + 64 * q] = xu;
    }
    if (lane == 0) lse[row] = m + logf(s);
}

// ---------------------------------------------------------------------------
// K2/K4: batched bf16 GEMM, C[m][n] = sum_k A[m][k]*B[n][k], fused epilogues.
// 256x256 tile, BK=32, 8 waves (2Mx4N), per-wave 128x64 via 8x4 mfma 16x16x32.
// Triple-buffered LDS (3 x 32KB): stage for tile t+2 never touches the buffer
// tile t reads -> ONE raw s_barrier per K-tile (mid-tile, after lgkmcnt(0) +
// counted vmcnt(4)). Reads for tile t+1 issue right after the barrier so the
// LDS pipe runs under q1(t)/q0(t+1) MFMA. Counted lgkmcnt(4) gates q0 (first
// 8 of 12 in-order reads = bv+a0). Register frags double-buffered (bv,a0).
// ---------------------------------------------------------------------------
#define SB0() __builtin_amdgcn_sched_barrier(0)

#define STEP(tt, bvC, a0C, bvN, a0N)                                            \
  {                                                                             \
    int brN = (brC == 2) ? 0 : brC + 1;                                         \
    int bw  = (brN == 2) ? 0 : brN + 1;                                         \
    asm volatile("s_waitcnt lgkmcnt(4)" ::: "memory");                          \
    SB0();                                                                      \
    __builtin_amdgcn_s_setprio(1);                                              \
    _Pragma("unroll") for (int i2 = 0; i2 < 4; ++i2)                            \
    _Pragma("unroll") for (int j = 0; j < 4; ++j)                               \
      acc[i2][j] = __builtin_amdgcn_mfma_f32_16x16x32_bf16(a0C[i2], bvC[j],     \
                                                           acc[i2][j], 0, 0, 0);\
    __builtin_amdgcn_s_setprio(0);                                              \
    if ((tt) + 2 < 32) stage(bw, (tt) + 2);                                     \
    asm volatile("s_waitcnt lgkmcnt(0)" ::: "memory");                          \
    if ((tt) < 30)        asm volatile("s_waitcnt vmcnt(4)" ::: "memory");      \
    else if ((tt) == 30)  asm volatile("s_waitcnt vmcnt(0)" ::: "memory");      \
    SB0();                                                                      \
    __builtin_amdgcn_s_barrier();                                               \
    SB0();                                                                      \
    if ((tt) + 1 < 32) {                                                        \
      _Pragma("unroll") for (int j = 0; j < 4; ++j)  bvN[j]  = lB(brN, j);      \
      _Pragma("unroll") for (int i2 = 0; i2 < 4; ++i2) a0N[i2] = lA(brN, 0, i2);\
    }                                                                           \
    SB0();                                                                      \
    __builtin_amdgcn_s_setprio(1);                                              \
    _Pragma("unroll") for (int i2 = 0; i2 < 4; ++i2)                            \
    _Pragma("unroll") for (int j = 0; j < 4; ++j)                               \
      acc[4 + i2][j] = __builtin_amdgcn_mfma_f32_16x16x32_bf16(a1[i2], bvC[j],  \
                                                        acc[4 + i2][j], 0, 0, 0);\
    __builtin_amdgcn_s_setprio(0);                                              \
    if ((tt) + 1 < 32) {                                                        \
      _Pragma("unroll") for (int i2 = 0; i2 < 4; ++i2) a1[i2] = lA(brN, 1, i2); \
    }                                                                           \
    brC = brN;                                                                  \
  }

template<int MODE>
__global__ __launch_bounds__(512, 2) void gemm_bt(const unsigned short* __restrict__ Ag,
        const unsigned short* __restrict__ Bg, void* __restrict__ Cg,
        const float* __restrict__ lse, float* __restrict__ rowsum) {
    const int K = 1024;
    int b = blockIdx.z;
    const unsigned short* A  = Ag + (size_t)b * N_ * K;
    const unsigned short* Bm = Bg + (size_t)b * N_ * K;
    int m0 = blockIdx.y * 256, n0 = blockIdx.x * 256;

    // A bufs @ 0,16K,32K ; B bufs @ 48K,64K,80K  (96 KB dynamic LDS)
    extern __shared__ char lds[];

    int t = threadIdx.x;
    int wave = t >> 6, lane = t & 63;
    int wr = wave >> 2, wc = wave & 3;        // 2 x 4 wave grid
    int fm = lane & 15, gf = lane >> 4;

    f32x4 acc[8][4];
    #pragma unroll
    for (int i = 0; i < 8; i++)
        #pragma unroll
        for (int j = 0; j < 4; j++)
            #pragma unroll
            for (int r = 0; r < 4; r++) acc[i][j][r] = 0.0f;

    // --- staging slice (per thread): chunk = 128 rows x 64B; 4 glds/tile ---
    int rr = t >> 2, s = t & 3;
    int sg = s ^ ((rr >> 1) & 3);             // inverse-swizzled source k-group
    int rbase = rr + (rr & 64);               // rows {0..63, 128..191}
    int row0s = rbase;                        // chunk 0
    int row1s = 64 + rbase;                   // chunk 1: rows {64..127, 192..255}
    const unsigned short* pA0 = A  + (size_t)(m0 + row0s) * K + sg * 8;
    const unsigned short* pA1 = A  + (size_t)(m0 + row1s) * K + sg * 8;
    const unsigned short* pB0 = Bm + (size_t)(n0 + row0s) * K + sg * 8;
    const unsigned short* pB1 = Bm + (size_t)(n0 + row1s) * K + sg * 8;
    int dA0 = row0s * 64 + s * 16;            // byte offsets within a buffer
    int dA1 = row1s * 64 + s * 16;

    auto stage = [&](int bw, int tg) {
        char* ab = lds + bw * 16384;
        char* bb = lds + 49152 + bw * 16384;
        gld_lds16(pA0 + tg * 32, ab + dA0);
        gld_lds16(pA1 + tg * 32, ab + dA1);
        gld_lds16(pB0 + tg * 32, bb + dA0);
        gld_lds16(pB1 + tg * 32, bb + dA1);
    };

    // --- fragment read addressing (swizzle term constant per lane) ---
    int slot = (gf ^ ((fm >> 1) & 3)) * 16;   // byte offset of 16B k-slot
    int arow = wr * 128 + fm;
    int brow = wc * 64 + fm;

    auto lA = [&](int br, int q, int i2) {
        return *(const bf16x8*)(lds + br * 16384 + (arow + q * 64 + i2 * 16) * 64 + slot);
    };
    auto lB = [&](int br, int j) {
        return *(const bf16x8*)(lds + 49152 + br * 16384 + (brow + j * 16) * 64 + slot);
    };

    bf16x8 bvA[4], a0A[4], bvB[4], a0B[4], a1[4];

    // prologue: tiles 0,1 staged; tile 0 landed; initial reads issued.
    stage(0, 0);
    stage(1, 1);
    asm volatile("s_waitcnt vmcnt(4)" ::: "memory");
    __builtin_amdgcn_s_barrier();
    SB0();
    #pragma unroll
    for (int j = 0; j < 4; ++j)  bvA[j]  = lB(0, j);
    #pragma unroll
    for (int i2 = 0; i2 < 4; ++i2) a0A[i2] = lA(0, 0, i2);
    SB0();
    #pragma unroll
    for (int i2 = 0; i2 < 4; ++i2) a1[i2] = lA(0, 1, i2);

    int brC = 0;
    for (int tp = 0; tp < 16; ++tp) {
        STEP(2 * tp,     bvA, a0A, bvB, a0B);
        STEP(2 * tp + 1, bvB, a0B, bvA, a0A);
    }

    // epilogue: C/D layout col=lane&15, row=(lane>>4)*4+reg
    int cr = (lane >> 4) * 4;
    int cc = lane & 15;

    if (MODE == 0) {
        unsigned short* Co = (unsigned short*)Cg + (size_t)b * (size_t)N_ * N_;
        float lsev[4];
        #pragma unroll
        for (int j = 0; j < 4; j++) lsev[j] = lse[b * N_ + n0 + wc * 64 + j * 16 + cc];
        float rsum[32];
        #pragma unroll
        for (int q = 0; q < 32; q++) rsum[q] = 0.0f;
        #pragma unroll
        for (int i = 0; i < 8; i++) {
            #pragma unroll
            for (int r = 0; r < 4; r++) {
                int row = m0 + wr * 128 + i * 16 + cr + r;
                size_t ro = (size_t)row * N_;
                #pragma unroll
                for (int j = 0; j < 4; j++) {
                    int col = n0 + wc * 64 + j * 16 + cc;
                    float ev = __expf(acc[i][j][r] - lsev[j]);   // always in [e^-14, e^-1]
                    unsigned short eb = f2bf(ev);
                    union { unsigned u; float f; } bk; bk.u = ((unsigned)eb) << 16;
                    Co[ro + col] = eb;
                    rsum[i * 4 + r] += bk.f;                     // sum the ROUNDED value
                }
            }
        }
        #pragma unroll
        for (int q = 0; q < 32; q++) {
            float sv = rsum[q];
            sv += __shfl_xor(sv, 1, 64);
            sv += __shfl_xor(sv, 2, 64);
            sv += __shfl_xor(sv, 4, 64);
            sv += __shfl_xor(sv, 8, 64);
            rsum[q] = sv;
        }
        if (cc == 0) {
            #pragma unroll
            for (int q = 0; q < 32; q++) {
                int row = m0 + wr * 128 + (q >> 2) * 16 + cr + (q & 3);
                atomicAdd(&rowsum[b * N_ + row], rsum[q]);
            }
        }
    } else {
        float* Co = (float*)Cg + (size_t)b * (size_t)N_ * N_;
        #pragma unroll
        for (int i = 0; i < 8; i++) {
            #pragma unroll
            for (int r = 0; r < 4; r++) {
                int row = m0 + wr * 128 + i * 16 + cr + r;
                float inv = 1.0f / rowsum[b * N_ + row];
                size_t ro = (size_t)row * N_;
                #pragma unroll
                for (int j = 0; j < 4; j++) {
                    int col = n0 + wc * 64 + j * 16 + cc;
                    Co[ro + col] = acc[i][j][r] * inv;
                }
            }
        }
    }
}

// ---------------------------------------------------------------------------
// K3: bf16 transpose per batch: xb[b][j][d] -> xbT[b][d][j], 64x64 tiles.
// ---------------------------------------------------------------------------
__global__ __launch_bounds__(256) void transpose_kernel(const unsigned short* __restrict__ in,
        unsigned short* __restrict__ out) {
    int b  = blockIdx.z;
    int j0 = blockIdx.y * 64;
    int d0 = blockIdx.x * 64;
    __shared__ unsigned short tile[64][66];
    const unsigned short* ip = in + ((size_t)b * N_ + j0) * D_ + d0;
    int t = threadIdx.x;
    #pragma unroll
    for (int c = t; c < 512; c += 256) {
        int r = c >> 3, col = (c & 7) * 8;
        uint4 val = *(const uint4*)(ip + (size_t)r * D_ + col);
        unsigned int* dst = (unsigned int*)&tile[r][col];
        dst[0] = val.x; dst[1] = val.y; dst[2] = val.z; dst[3] = val.w;
    }
    __syncthreads();
    unsigned short* op = out + ((size_t)b * D_ + d0) * N_ + j0;
    #pragma unroll
    for (int c = t; c < 512; c += 256) {
        int r = c >> 3, col = (c & 7) * 8;
        unsigned short vals[8];
        #pragma unroll
        for (int k = 0; k < 8; k++) vals[k] = tile[col + k][r];
        uint4 o;
        o.x = (unsigned)vals[0] | ((unsigned)vals[1] << 16);
        o.y = (unsigned)vals[2] | ((unsigned)vals[3] << 16);
        o.z = (unsigned)vals[4] | ((unsigned)vals[5] << 16);
        o.w = (unsigned)vals[6] | ((unsigned)vals[7] << 16);
        *(uint4*)(op + (size_t)r * N_ + col) = o;
    }
}

extern "C" void kernel_launch(void* const* d_in, const int* in_sizes, int n_in,
                              void* d_out, int out_size, void* d_ws, size_t ws_size,
                              hipStream_t stream) {
    const float* x = (const float*)d_in[0];
    float* out = (float*)d_out;
    char* ws = (char*)d_ws;

    // layout: [pb 64M][xb 64M][xbT 64M][attnE 64M][lse 128K][rowsum 128K]
    unsigned short* pb    = (unsigned short*)(ws);
    unsigned short* xb    = (unsigned short*)(ws + 67108864ULL);
    unsigned short* xbT   = (unsigned short*)(ws + 134217728ULL);
    unsigned short* attnE = (unsigned short*)(ws + 201326592ULL);
    float*          lse   = (float*)(ws + 268435456ULL);
    float*          rowsum= (float*)(ws + 268566528ULL);

    hipMemsetAsync(rowsum, 0, B_ * N_ * sizeof(float), stream);
    prep_kernel<<<dim3(B_ * N_ / 4), 256, 0, stream>>>(x, pb, xb, lse);
    transpose_kernel<<<dim3(16, 16, B_), 256, 0, stream>>>(xb, xbT);
    gemm_bt<0><<<dim3(4, 4, B_), 512, 98304, stream>>>(pb, xb, attnE, lse, rowsum);
    gemm_bt<1><<<dim3(4, 4, B_), 512, 98304, stream>>>(attnE, xbT, out, nullptr, rowsum);
}

// Round 3
// 419.875 us; speedup vs baseline: 1.1435x; 1.0011x over previous
//
#include <hip/hip_runtime.h>
#include <hip/hip_bf16.h>
#include <stdint.h>

#define B_ 32
#define N_ 1024
#define D_ 1024

typedef __bf16 bf16x8 __attribute__((ext_vector_type(8)));
typedef float f32x4 __attribute__((ext_vector_type(4)));

static __device__ __forceinline__ unsigned short f2bf(float f) {
    union { float f; unsigned u; } v; v.f = f;
    unsigned r = v.u + 0x7fffu + ((v.u >> 16) & 1u);   // round-to-nearest-even
    return (unsigned short)(r >> 16);
}

static __device__ __forceinline__ void gld_lds16(const void* g, void* l) {
    __builtin_amdgcn_global_load_lds(
        (const __attribute__((address_space(1))) void*)g,
        (__attribute__((address_space(3))) void*)l, 16, 0, 0);
}

// ---------------------------------------------------------------------------
// K1: wave-per-row softmax stats. 4 rows/block, no __syncthreads.
// ---------------------------------------------------------------------------
__global__ __launch_bounds__(256) void prep_kernel(const float* __restrict__ x,
        unsigned short* __restrict__ pb, unsigned short* __restrict__ xb,
        float* __restrict__ lse) {
    int row  = blockIdx.x * 4 + (threadIdx.x >> 6);
    int lane = threadIdx.x & 63;
    const float4* xr = (const float4*)(x + (size_t)row * D_);

    float4 v[4];
    #pragma unroll
    for (int q = 0; q < 4; q++) v[q] = xr[lane + 64 * q];

    float m = -1e30f;
    #pragma unroll
    for (int q = 0; q < 4; q++)
        m = fmaxf(m, fmaxf(fmaxf(v[q].x, v[q].y), fmaxf(v[q].z, v[q].w)));
    #pragma unroll
    for (int o = 1; o < 64; o <<= 1) m = fmaxf(m, __shfl_xor(m, o, 64));

    float4 e[4];
    float s = 0.0f;
    #pragma unroll
    for (int q = 0; q < 4; q++) {
        e[q].x = __expf(v[q].x - m); e[q].y = __expf(v[q].y - m);
        e[q].z = __expf(v[q].z - m); e[q].w = __expf(v[q].w - m);
        s += e[q].x + e[q].y + e[q].z + e[q].w;
    }
    #pragma unroll
    for (int o = 1; o < 64; o <<= 1) s += __shfl_xor(s, o, 64);
    float inv = 1.0f / s;

    ushort4* pr = (ushort4*)(pb + (size_t)row * D_);
    ushort4* xw = (ushort4*)(xb + (size_t)row * D_);
    #pragma unroll
    for (int q = 0; q < 4; q++) {
        ushort4 pu, xu;
        pu.x = f2bf(e[q].x * inv); pu.y = f2bf(e[q].y * inv);
        pu.z = f2bf(e[q].z * inv); pu.w = f2bf(e[q].w * inv);
        xu.x = f2bf(v[q].x); xu.y = f2bf(v[q].y);
        xu.z = f2bf(v[q].z); xu.w = f2bf(v[q].w);
        pr[lane + 64 * q] = pu;
        xw[lane + 64 * q] = xu;
    }
    if (lane == 0) lse[row] = m + logf(s);
}

// ---------------------------------------------------------------------------
// K2/K4: batched bf16 GEMM, C[m][n] = sum_k A[m][k]*B[n][k], fused epilogues.
// 256x256 tile, BK=32, 8 waves (2Mx4N), per-wave 128x64 via 8x4 mfma 16x16x32.
// 8-phase-style schedule (m201 template): per K-tile, TWO short phases, each
// {ds_read subtile + 2 global_load_lds -> barrier -> lgkmcnt(0) -> setprio ->
// 16 MFMA -> setprio -> barrier}. QUAD-buffered LDS (4 x 32KB): DMA staged
// 3 tiles ahead, counted vmcnt(8) once per K-tile (loads waited were issued
// 4-6 phases = ~1500+ cyc earlier -> HBM latency fully covered; never drain
// to 0 until the tail). Zero-conflict LDS layout: 64B rows per 32-k plane,
// k-group XOR swizzle on DMA source + read slot (measured 0 conflicts).
// XCD-aware bijective block swizzle: each XCD gets contiguous batches.
// MODE 0 (gemm1): e = exp(acc - lse[col]) -> bf16 store + rowsum atomics.
// MODE 1 (gemm2): out = acc / rowsum[row], fp32 store.
// ---------------------------------------------------------------------------
#define SB0() __builtin_amdgcn_sched_barrier(0)
#define VM8 asm volatile("s_waitcnt vmcnt(8)" ::: "memory")
#define VM4 asm volatile("s_waitcnt vmcnt(4)" ::: "memory")
#define VM0 asm volatile("s_waitcnt vmcnt(0)" ::: "memory")
#define VMN

#define TILE(tt, rB, wB, DOSTAGE, VM)                                           \
  {                                                                             \
    _Pragma("unroll") for (int j = 0; j < 4; ++j)  bv[j] = lB(rB, j);           \
    _Pragma("unroll") for (int i2 = 0; i2 < 4; ++i2) a0[i2] = lA(rB, 0, i2);    \
    if (DOSTAGE) stageA(wB, (tt) + 3);                                          \
    SB0();                                                                      \
    __builtin_amdgcn_s_barrier();                                               \
    asm volatile("s_waitcnt lgkmcnt(0)" ::: "memory");                          \
    SB0();                                                                      \
    __builtin_amdgcn_s_setprio(1);                                              \
    _Pragma("unroll") for (int i2 = 0; i2 < 4; ++i2)                            \
      _Pragma("unroll") for (int j = 0; j < 4; ++j)                             \
        acc[i2][j] = __builtin_amdgcn_mfma_f32_16x16x32_bf16(a0[i2], bv[j],     \
                                                             acc[i2][j], 0, 0, 0); \
    __builtin_amdgcn_s_setprio(0);                                              \
    SB0();                                                                      \
    __builtin_amdgcn_s_barrier();                                               \
    _Pragma("unroll") for (int i2 = 0; i2 < 4; ++i2) a1[i2] = lA(rB, 1, i2);    \
    if (DOSTAGE) stageB(wB, (tt) + 3);                                          \
    VM;                                                                         \
    SB0();                                                                      \
    __builtin_amdgcn_s_barrier();                                               \
    asm volatile("s_waitcnt lgkmcnt(0)" ::: "memory");                          \
    SB0();                                                                      \
    __builtin_amdgcn_s_setprio(1);                                              \
    _Pragma("unroll") for (int i2 = 0; i2 < 4; ++i2)                            \
      _Pragma("unroll") for (int j = 0; j < 4; ++j)                             \
        acc[4 + i2][j] = __builtin_amdgcn_mfma_f32_16x16x32_bf16(a1[i2], bv[j], \
                                                        acc[4 + i2][j], 0, 0, 0); \
    __builtin_amdgcn_s_setprio(0);                                              \
    SB0();                                                                      \
    __builtin_amdgcn_s_barrier();                                               \
  }

template<int MODE>
__global__ __launch_bounds__(512, 2) void gemm_bt(const unsigned short* __restrict__ Ag,
        const unsigned short* __restrict__ Bg, void* __restrict__ Cg,
        const float* __restrict__ lse, float* __restrict__ rowsum) {
    const int K = 1024;

    // XCD-aware bijective swizzle: hw linear id h -> logical l; XCD = h%8
    // gets 64 consecutive logical blocks = 4 whole batches (panel L2 reuse).
    int h = blockIdx.x + 4 * blockIdx.y + 16 * blockIdx.z;   // 0..511
    int l = (h & 7) * 64 + (h >> 3);
    int b  = l >> 4;
    int m0 = ((l >> 2) & 3) * 256;
    int n0 = (l & 3) * 256;

    const unsigned short* A  = Ag + (size_t)b * N_ * K;
    const unsigned short* Bm = Bg + (size_t)b * N_ * K;

    // 4 buffers x 32KB: buf w -> A plane at w*32768, B plane at +16384.
    extern __shared__ char lds[];

    int t = threadIdx.x;
    int wave = t >> 6, lane = t & 63;
    int wr = wave >> 2, wc = wave & 3;        // 2 x 4 wave grid
    int fm = lane & 15, gf = lane >> 4;

    f32x4 acc[8][4];
    #pragma unroll
    for (int i = 0; i < 8; i++)
        #pragma unroll
        for (int j = 0; j < 4; j++)
            #pragma unroll
            for (int r = 0; r < 4; r++) acc[i][j][r] = 0.0f;

    // --- staging slice: per K-tile, A = 2 loads/thread, B = 2 loads/thread ---
    int rr = t >> 2, s = t & 3;               // rr 0..127, s 0..3
    int sg = s ^ ((rr >> 1) & 3);             // inverse-swizzled source k-group
    const unsigned short* pA0 = A  + (size_t)(m0 + rr) * K + sg * 8;
    const unsigned short* pA1 = A  + (size_t)(m0 + 128 + rr) * K + sg * 8;
    const unsigned short* pB0 = Bm + (size_t)(n0 + rr) * K + sg * 8;
    const unsigned short* pB1 = Bm + (size_t)(n0 + 128 + rr) * K + sg * 8;
    int d0 = rr * 64 + s * 16;                // byte offsets within a plane
    int d1 = (128 + rr) * 64 + s * 16;

    auto stageA = [&](int w, int tg) {
        char* ab = lds + w * 32768;
        gld_lds16(pA0 + tg * 32, ab + d0);
        gld_lds16(pA1 + tg * 32, ab + d1);
    };
    auto stageB = [&](int w, int tg) {
        char* bb = lds + w * 32768 + 16384;
        gld_lds16(pB0 + tg * 32, bb + d0);
        gld_lds16(pB1 + tg * 32, bb + d1);
    };

    // --- fragment reads (zero-conflict slot swizzle, constant per lane) ---
    int slot = (gf ^ ((fm >> 1) & 3)) * 16;
    auto lA = [&](int br, int q, int i2) {
        return *(const bf16x8*)(lds + br * 32768 +
                 (wr * 128 + (q * 4 + i2) * 16 + fm) * 64 + slot);
    };
    auto lB = [&](int br, int j) {
        return *(const bf16x8*)(lds + br * 32768 + 16384 +
                 (wc * 64 + j * 16 + fm) * 64 + slot);
    };

    bf16x8 bv[4], a0[4], a1[4];

    // prologue: stage tiles 0,1,2 (3 deep); wait tile 0 (first 4 loads).
    stageA(0, 0); stageB(0, 0);
    stageA(1, 1); stageB(1, 1);
    stageA(2, 2); stageB(2, 2);
    VM8;
    __builtin_amdgcn_s_barrier();

    for (int tp = 0; tp < 7; ++tp) {
        int t0 = tp * 4;
        TILE(t0 + 0, 0, 3, 1, VM8);
        TILE(t0 + 1, 1, 0, 1, VM8);
        TILE(t0 + 2, 2, 1, 1, VM8);
        TILE(t0 + 3, 3, 2, 1, VM8);
    }
    TILE(28, 0, 3, 1, VM8);                   // stages tile 31
    TILE(29, 1, 0, 0, VM4);
    TILE(30, 2, 1, 0, VM0);
    TILE(31, 3, 2, 0, VMN);

    // epilogue: C/D layout col=lane&15, row=(lane>>4)*4+reg
    int cr = (lane >> 4) * 4;
    int cc = lane & 15;

    if (MODE == 0) {
        unsigned short* Co = (unsigned short*)Cg + (size_t)b * (size_t)N_ * N_;
        float lsev[4];
        #pragma unroll
        for (int j = 0; j < 4; j++) lsev[j] = lse[b * N_ + n0 + wc * 64 + j * 16 + cc];
        float rsum[32];
        #pragma unroll
        for (int q = 0; q < 32; q++) rsum[q] = 0.0f;
        #pragma unroll
        for (int i = 0; i < 8; i++) {
            #pragma unroll
            for (int r = 0; r < 4; r++) {
                int row = m0 + wr * 128 + i * 16 + cr + r;
                size_t ro = (size_t)row * N_;
                #pragma unroll
                for (int j = 0; j < 4; j++) {
                    int col = n0 + wc * 64 + j * 16 + cc;
                    float ev = __expf(acc[i][j][r] - lsev[j]);   // always in [e^-14, e^-1]
                    unsigned short eb = f2bf(ev);
                    union { unsigned u; float f; } bk; bk.u = ((unsigned)eb) << 16;
                    Co[ro + col] = eb;
                    rsum[i * 4 + r] += bk.f;                     // sum the ROUNDED value
                }
            }
        }
        #pragma unroll
        for (int q = 0; q < 32; q++) {
            float sv = rsum[q];
            sv += __shfl_xor(sv, 1, 64);
            sv += __shfl_xor(sv, 2, 64);
            sv += __shfl_xor(sv, 4, 64);
            sv += __shfl_xor(sv, 8, 64);
            rsum[q] = sv;
        }
        if (cc == 0) {
            #pragma unroll
            for (int q = 0; q < 32; q++) {
                int row = m0 + wr * 128 + (q >> 2) * 16 + cr + (q & 3);
                atomicAdd(&rowsum[b * N_ + row], rsum[q]);
            }
        }
    } else {
        float* Co = (float*)Cg + (size_t)b * (size_t)N_ * N_;
        #pragma unroll
        for (int i = 0; i < 8; i++) {
            #pragma unroll
            for (int r = 0; r < 4; r++) {
                int row = m0 + wr * 128 + i * 16 + cr + r;
                float inv = 1.0f / rowsum[b * N_ + row];
                size_t ro = (size_t)row * N_;
                #pragma unroll
                for (int j = 0; j < 4; j++) {
                    int col = n0 + wc * 64 + j * 16 + cc;
                    Co[ro + col] = acc[i][j][r] * inv;
                }
            }
        }
    }
}

// ---------------------------------------------------------------------------
// K3: bf16 transpose per batch: xb[b][j][d] -> xbT[b][d][j], 64x64 tiles.
// ---------------------------------------------------------------------------
__global__ __launch_bounds__(256) void transpose_kernel(const unsigned short* __restrict__ in,
        unsigned short* __restrict__ out) {
    int b  = blockIdx.z;
    int j0 = blockIdx.y * 64;
    int d0 = blockIdx.x * 64;
    __shared__ unsigned short tile[64][66];
    const unsigned short* ip = in + ((size_t)b * N_ + j0) * D_ + d0;
    int t = threadIdx.x;
    #pragma unroll
    for (int c = t; c < 512; c += 256) {
        int r = c >> 3, col = (c & 7) * 8;
        uint4 val = *(const uint4*)(ip + (size_t)r * D_ + col);
        unsigned int* dst = (unsigned int*)&tile[r][col];
        dst[0] = val.x; dst[1] = val.y; dst[2] = val.z; dst[3] = val.w;
    }
    __syncthreads();
    unsigned short* op = out + ((size_t)b * D_ + d0) * N_ + j0;
    #pragma unroll
    for (int c = t; c < 512; c += 256) {
        int r = c >> 3, col = (c & 7) * 8;
        unsigned short vals[8];
        #pragma unroll
        for (int k = 0; k < 8; k++) vals[k] = tile[col + k][r];
        uint4 o;
        o.x = (unsigned)vals[0] | ((unsigned)vals[1] << 16);
        o.y = (unsigned)vals[2] | ((unsigned)vals[3] << 16);
        o.z = (unsigned)vals[4] | ((unsigned)vals[5] << 16);
        o.w = (unsigned)vals[6] | ((unsigned)vals[7] << 16);
        *(uint4*)(op + (size_t)r * N_ + col) = o;
    }
}

extern "C" void kernel_launch(void* const* d_in, const int* in_sizes, int n_in,
                              void* d_out, int out_size, void* d_ws, size_t ws_size,
                              hipStream_t stream) {
    const float* x = (const float*)d_in[0];
    float* out = (float*)d_out;
    char* ws = (char*)d_ws;

    // layout: [pb 64M][xb 64M][xbT 64M][attnE 64M][lse 128K][rowsum 128K]
    unsigned short* pb    = (unsigned short*)(ws);
    unsigned short* xb    = (unsigned short*)(ws + 67108864ULL);
    unsigned short* xbT   = (unsigned short*)(ws + 134217728ULL);
    unsigned short* attnE = (unsigned short*)(ws + 201326592ULL);
    float*          lse   = (float*)(ws + 268435456ULL);
    float*          rowsum= (float*)(ws + 268566528ULL);

    hipMemsetAsync(rowsum, 0, B_ * N_ * sizeof(float), stream);
    prep_kernel<<<dim3(B_ * N_ / 4), 256, 0, stream>>>(x, pb, xb, lse);
    transpose_kernel<<<dim3(16, 16, B_), 256, 0, stream>>>(xb, xbT);
    gemm_bt<0><<<dim3(4, 4, B_), 512, 131072, stream>>>(pb, xb, attnE, lse, rowsum);
    gemm_bt<1><<<dim3(4, 4, B_), 512, 131072, stream>>>(attnE, xbT, out, nullptr, rowsum);
}